// Round 10
// baseline (188.589 us; speedup 1.0000x reference)
//
#include <hip/hip_runtime.h>
#include <hip/hip_cooperative_groups.h>

namespace cg = cooperative_groups;

// Sizes fixed by the problem.
#define B   32
#define S   128
#define IN  64
#define ROWS (B*S)      // 4096
#define K1  (S*IN)      // 8192
#define KCH 128         // P-GEMM k-chunks (64 k each)
#define GRID 512        // 2 blocks/CU -> 2 waves/SIMD

__device__ __forceinline__ int rfl(int x) { return __builtin_amdgcn_readfirstlane(x); }

// ---------------------------------------------------------------------------
// Fused cooperative kernel: 512 blocks x 256 threads, 3 phases, 2 grid syncs.
// LDS-free throughout: wave-uniform operands -> scalar pipe; per-lane
// contiguous operands -> float4 VGPR-cached loads.
// ---------------------------------------------------------------------------
__global__ __launch_bounds__(256, 2) void fused_kernel(
    const float* __restrict__ h,  const float* __restrict__ W0,
    const float* __restrict__ b0, const float* __restrict__ Ws,
    const float* __restrict__ bs, const float* __restrict__ W1,
    const float* __restrict__ b1,
    float* __restrict__ U1T, float* __restrict__ Ab,
    float* __restrict__ Df,  float* __restrict__ C,
    float* __restrict__ P,   float* __restrict__ out)
{
    cg::grid_group grid = cg::this_grid();
    const int bid  = blockIdx.x;
    const int tid  = threadIdx.x;
    const int lane = tid & 63;
    const int w    = rfl(tid >> 6);            // wave id, uniform

    // ======== Phase 1: per-row Ab/C/Df (8 rows/block) + U1T (8 outs/block) ==
    {
        const int row0 = bid * 8 + w * 2;      // this wave's 2 rows (uniform)
        // 'bsi,oi->bso': o indexes ROWS of W0/Ws -> lane's weights are row lane.
        const float4* w0row = (const float4*)(W0 + (size_t)lane * 128);
        const float4* wsrow = (const float4*)(Ws + (size_t)lane * 64);

        float a[2] = {0,0}, c[2] = {0,0}, sf[2] = {0,0};
        #pragma unroll
        for (int ic = 0; ic < 4; ++ic) {       // i-chunks of 16 (keeps VGPRs low)
            const int i0 = ic * 16;
            float wa[16], wb[16], wsv[16];
            #pragma unroll
            for (int q = 0; q < 4; ++q) {      // per-lane contiguous 16B loads
                const float4 va = w0row[ic * 4 + q];
                const float4 vb = w0row[16 + ic * 4 + q];
                const float4 vs = wsrow[ic * 4 + q];
                wa [q*4] = va.x; wa [q*4+1] = va.y; wa [q*4+2] = va.z; wa [q*4+3] = va.w;
                wb [q*4] = vb.x; wb [q*4+1] = vb.y; wb [q*4+2] = vb.z; wb [q*4+3] = vb.w;
                wsv[q*4] = vs.x; wsv[q*4+1] = vs.y; wsv[q*4+2] = vs.z; wsv[q*4+3] = vs.w;
            }
            #pragma unroll
            for (int r = 0; r < 2; ++r) {
                const float* hp = h + (size_t)(row0 + r) * 64 + i0;  // uniform -> s_load
                #pragma unroll
                for (int j = 0; j < 16; ++j) {
                    const float hv = hp[j];
                    a [r] += hv * wa [j];
                    c [r] += hv * wb [j];
                    sf[r] += hv * wsv[j];
                }
            }
        }
        const float b0v = b0[lane], bsv = bs[lane];
        #pragma unroll
        for (int r = 0; r < 2; ++r) {
            const int row = row0 + r;
            const float ab = a[r] + b0v;
            Ab[row * 64 + lane] = ab;          // coalesced stores
            C [row * 64 + lane] = c[r];
            Df[row * 64 + lane] = sf[r] + bsv - ab - c[r];
        }

        // U1T[o][o2] = sum_t W1[o2, t*64+o]; 8 outputs/block, 32 lanes each.
        const int g   = bid * 8 + (tid >> 5);  // 0..4095
        const int o2  = g >> 6, o = g & 63;
        const int sub = tid & 31;
        float acc = 0.f;
        #pragma unroll
        for (int u = 0; u < 4; ++u)
            acc += W1[(size_t)o2 * K1 + (sub + 32 * u) * 64 + o];
        #pragma unroll
        for (int m = 16; m; m >>= 1) acc += __shfl_xor(acc, m);  // within 32-group
        if (sub == 0) U1T[o * 64 + o2] = acc;
    }

    grid.sync();

    // ======== Phase 2: P[b][o2][kc] partial GEMM, (kc x b-quarter) blocks ====
    {
        const int kc = bid >> 2, q = bid & 3;  // kc: 0..127, q: b-quarter
        const int k0 = kc * 64;
        const float4* wrow = (const float4*)(W1 + (size_t)lane * K1 + k0);

        float acc[2] = {0, 0};                 // b = q*8 + w + 4*pp
        #pragma unroll
        for (int kq = 0; kq < 16; ++kq) {
            const float4 w4 = wrow[kq];        // per-lane contiguous, L2-resident
            #pragma unroll
            for (int pp = 0; pp < 2; ++pp) {
                const int b = q * 8 + w + 4 * pp;
                const float* cb = C + (size_t)b * K1 + k0 + kq * 4;  // uniform -> s_load
                acc[pp] += cb[0] * w4.x + cb[1] * w4.y + cb[2] * w4.z + cb[3] * w4.w;
            }
        }
        #pragma unroll
        for (int pp = 0; pp < 2; ++pp) {
            const int b = q * 8 + w + 4 * pp;
            P[((size_t)(b * 64 + lane)) * KCH + kc] = acc[pp];
        }
    }

    grid.sync();

    // ======== Phase 3: out, (s x b-quarter) blocks, 2 b per thread ==========
    {
        const int s = bid >> 2, q = bid & 3;
        const float b1v = b1[lane];            // lane = o2

        float acc[2];
        #pragma unroll
        for (int pp = 0; pp < 2; ++pp) {       // D-fold: per-lane contiguous b128
            const int b = q * 8 + w + 4 * pp;
            const float4* pf = (const float4*)(P + ((size_t)(b * 64 + lane)) * KCH);
            float s0 = 0, s1 = 0, s2 = 0, s3 = 0;
            #pragma unroll
            for (int u = 0; u < 32; ++u) {
                const float4 v = pf[u];
                s0 += v.x; s1 += v.y; s2 += v.z; s3 += v.w;
            }
            acc[pp] = b1v + ((s0 + s1) + (s2 + s3));
        }

        #pragma unroll
        for (int hh = 0; hh < 2; ++hh) {       // two 32-wide o-halves
            const int o0 = hh * 32;
            float u[32], wc[32];
            #pragma unroll
            for (int j = 0; j < 32; ++j)
                u[j] = U1T[(o0 + j) * 64 + lane];           // coalesced across lanes
            const float4* wrow = (const float4*)(W1 + (size_t)lane * K1 + s * 64 + o0);
            #pragma unroll
            for (int qq = 0; qq < 8; ++qq) {   // per-lane contiguous 128B
                const float4 v = wrow[qq];
                wc[qq*4] = v.x; wc[qq*4+1] = v.y; wc[qq*4+2] = v.z; wc[qq*4+3] = v.w;
            }
            #pragma unroll
            for (int pp = 0; pp < 2; ++pp) {
                const int b = q * 8 + w + 4 * pp;
                const float* ap = Ab + ((size_t)(b * S + s)) * 64 + o0;  // uniform -> s_load
                const float* dp = Df + ((size_t)(b * S + s)) * 64 + o0;
                float t0 = 0.f;
                #pragma unroll
                for (int j = 0; j < 32; ++j)
                    t0 += ap[j] * u[j] + dp[j] * wc[j];
                acc[pp] += t0;
            }
        }

        #pragma unroll
        for (int pp = 0; pp < 2; ++pp) {
            const int b = q * 8 + w + 4 * pp;
            out[((size_t)(b * S + s)) * 64 + lane] = acc[pp];  // coalesced
        }
    }
}

// ---------------------------------------------------------------------------
extern "C" void kernel_launch(void* const* d_in, const int* in_sizes, int n_in,
                              void* d_out, int out_size, void* d_ws, size_t ws_size,
                              hipStream_t stream)
{
    const float* h  = (const float*)d_in[0];
    const float* W0 = (const float*)d_in[1];
    const float* b0 = (const float*)d_in[2];
    const float* Ws = (const float*)d_in[3];
    const float* bs = (const float*)d_in[4];
    const float* W1 = (const float*)d_in[5];
    const float* b1 = (const float*)d_in[6];
    float* out = (float*)d_out;

    float* ws  = (float*)d_ws;
    float* U1T = ws;                       // 4096
    float* Ab  = U1T + 64 * 64;            // 262144
    float* Df  = Ab  + ROWS * 64;          // 262144
    float* C   = Df  + ROWS * 64;          // 262144
    float* P   = C   + ROWS * 64;          // 2048*128 = 262144
    // total: ~4.0 MB of d_ws; every element read is written first each call.

    void* args[] = {
        (void*)&h, (void*)&W0, (void*)&b0, (void*)&Ws, (void*)&bs,
        (void*)&W1, (void*)&b1,
        (void*)&U1T, (void*)&Ab, (void*)&Df, (void*)&C, (void*)&P, (void*)&out
    };
    hipLaunchCooperativeKernel((void*)fused_kernel, dim3(GRID), dim3(256),
                               args, 0, stream);
}

// Round 11
// 51.446 us; speedup vs baseline: 3.6657x; 3.6657x over previous
//
#include <hip/hip_runtime.h>

// Sizes fixed by the problem.
#define B   32
#define S   128
#define IN  64
#define ROWS (B*S)      // 4096
#define K1  (S*IN)      // 8192
#define KCH 128         // P-GEMM k-chunks (64 k each)

__device__ __forceinline__ int rfl(int x) { return __builtin_amdgcn_readfirstlane(x); }

// ---------------------------------------------------------------------------
// Kernel 1: "prep" — 512 blocks (2/CU). 8 rows/block + 8 U1T outputs/block.
//   LDS-free. 'bsi,oi->bso': o indexes ROWS of W0/Ws -> lane's weights are
//   row `lane` (per-lane contiguous float4). h rows wave-uniform -> s_load.
// ---------------------------------------------------------------------------
__global__ __launch_bounds__(256, 2) void prep_kernel(
    const float* __restrict__ h,  const float* __restrict__ W0,
    const float* __restrict__ b0, const float* __restrict__ Ws,
    const float* __restrict__ bs, const float* __restrict__ W1,
    float* __restrict__ U1T, float* __restrict__ Ab,
    float* __restrict__ Df,  float* __restrict__ C)
{
    const int bid  = blockIdx.x;
    const int tid  = threadIdx.x;
    const int lane = tid & 63;
    const int w    = rfl(tid >> 6);            // wave id, uniform

    const int row0 = bid * 8 + w * 2;          // this wave's 2 rows (uniform)
    const float4* w0row = (const float4*)(W0 + (size_t)lane * 128);
    const float4* wsrow = (const float4*)(Ws + (size_t)lane * 64);

    float a[2] = {0,0}, c[2] = {0,0}, sf[2] = {0,0};
    #pragma unroll
    for (int ic = 0; ic < 4; ++ic) {           // i-chunks of 16
        const int i0 = ic * 16;
        float wa[16], wb[16], wsv[16];
        #pragma unroll
        for (int q = 0; q < 4; ++q) {          // per-lane contiguous 16B loads
            const float4 va = w0row[ic * 4 + q];
            const float4 vb = w0row[16 + ic * 4 + q];
            const float4 vs = wsrow[ic * 4 + q];
            wa [q*4] = va.x; wa [q*4+1] = va.y; wa [q*4+2] = va.z; wa [q*4+3] = va.w;
            wb [q*4] = vb.x; wb [q*4+1] = vb.y; wb [q*4+2] = vb.z; wb [q*4+3] = vb.w;
            wsv[q*4] = vs.x; wsv[q*4+1] = vs.y; wsv[q*4+2] = vs.z; wsv[q*4+3] = vs.w;
        }
        #pragma unroll
        for (int r = 0; r < 2; ++r) {
            const float* hp = h + (size_t)(row0 + r) * 64 + i0;  // uniform -> s_load
            #pragma unroll
            for (int j = 0; j < 16; ++j) {
                const float hv = hp[j];
                a [r] += hv * wa [j];
                c [r] += hv * wb [j];
                sf[r] += hv * wsv[j];
            }
        }
    }
    const float b0v = b0[lane], bsv = bs[lane];
    #pragma unroll
    for (int r = 0; r < 2; ++r) {
        const int row = row0 + r;
        const float ab = a[r] + b0v;
        Ab[row * 64 + lane] = ab;              // coalesced stores
        C [row * 64 + lane] = c[r];
        Df[row * 64 + lane] = sf[r] + bsv - ab - c[r];
    }

    // U1T[o][o2] = sum_t W1[o2, t*64+o]; 8 outputs/block, 32 lanes each.
    const int g   = bid * 8 + (tid >> 5);      // 0..4095
    const int o2  = g >> 6, o = g & 63;
    const int sub = tid & 31;
    float acc = 0.f;
    #pragma unroll
    for (int u = 0; u < 4; ++u)
        acc += W1[(size_t)o2 * K1 + (sub + 32 * u) * 64 + o];
    #pragma unroll
    for (int m = 16; m; m >>= 1) acc += __shfl_xor(acc, m);  // within 32-group
    if (sub == 0) U1T[o * 64 + o2] = acc;
}

// ---------------------------------------------------------------------------
// Kernel 2: "mid" — 512 blocks (2/CU). P[b][o2][kc] partial GEMM.
//   block = (kc 0..127) x (b-quarter 0..3); 64 k per chunk; acc[2] per thread.
// ---------------------------------------------------------------------------
__global__ __launch_bounds__(256, 2) void mid_kernel(
    const float* __restrict__ C, const float* __restrict__ W1,
    float* __restrict__ P)
{
    const int bid  = blockIdx.x;
    const int tid  = threadIdx.x;
    const int lane = tid & 63;                 // = o2
    const int w    = rfl(tid >> 6);            // uniform

    const int kc = bid >> 2, q = bid & 3;      // kc: 0..127, q: b-quarter
    const int k0 = kc * 64;
    const float4* wrow = (const float4*)(W1 + (size_t)lane * K1 + k0);

    float acc[2] = {0, 0};                     // b = q*8 + w + 4*pp
    #pragma unroll
    for (int kq = 0; kq < 16; ++kq) {
        const float4 w4 = wrow[kq];            // per-lane contiguous, L2-resident
        #pragma unroll
        for (int pp = 0; pp < 2; ++pp) {
            const int b = q * 8 + w + 4 * pp;
            const float* cb = C + (size_t)b * K1 + k0 + kq * 4;  // uniform -> s_load
            acc[pp] += cb[0] * w4.x + cb[1] * w4.y + cb[2] * w4.z + cb[3] * w4.w;
        }
    }
    #pragma unroll
    for (int pp = 0; pp < 2; ++pp) {
        const int b = q * 8 + w + 4 * pp;
        P[((size_t)(b * 64 + lane)) * KCH + kc] = acc[pp];
    }
}

// ---------------------------------------------------------------------------
// Kernel 3: "finalk" — 512 blocks (2/CU). block = (s 0..127) x (b-quarter).
//   out[b,s,o2] = sum_kc P[b][o2][kc] + b1[o2]
//               + sum_o Ab[b,s,o]*U1T[o][o2] + Df[b,s,o]*W1[o2, s*64+o]
// ---------------------------------------------------------------------------
__global__ __launch_bounds__(256, 2) void final_kernel(
    const float* __restrict__ W1, const float* __restrict__ b1,
    const float* __restrict__ U1T, const float* __restrict__ Ab,
    const float* __restrict__ Df,  const float* __restrict__ P,
    float* __restrict__ out)
{
    const int bid  = blockIdx.x;
    const int tid  = threadIdx.x;
    const int lane = tid & 63;                 // = o2
    const int w    = rfl(tid >> 6);            // uniform

    const int s = bid >> 2, q = bid & 3;
    const float b1v = b1[lane];

    float acc[2];
    #pragma unroll
    for (int pp = 0; pp < 2; ++pp) {           // D-fold: per-lane contiguous b128
        const int b = q * 8 + w + 4 * pp;
        const float4* pf = (const float4*)(P + ((size_t)(b * 64 + lane)) * KCH);
        float s0 = 0, s1 = 0, s2 = 0, s3 = 0;
        #pragma unroll
        for (int u = 0; u < 32; ++u) {
            const float4 v = pf[u];
            s0 += v.x; s1 += v.y; s2 += v.z; s3 += v.w;
        }
        acc[pp] = b1v + ((s0 + s1) + (s2 + s3));
    }

    #pragma unroll
    for (int hh = 0; hh < 2; ++hh) {           // two 32-wide o-halves
        const int o0 = hh * 32;
        float u[32], wc[32];
        #pragma unroll
        for (int j = 0; j < 32; ++j)
            u[j] = U1T[(o0 + j) * 64 + lane];  // coalesced across lanes
        const float4* wrow = (const float4*)(W1 + (size_t)lane * K1 + s * 64 + o0);
        #pragma unroll
        for (int qq = 0; qq < 8; ++qq) {       // per-lane contiguous 128B
            const float4 v = wrow[qq];
            wc[qq*4] = v.x; wc[qq*4+1] = v.y; wc[qq*4+2] = v.z; wc[qq*4+3] = v.w;
        }
        #pragma unroll
        for (int pp = 0; pp < 2; ++pp) {
            const int b = q * 8 + w + 4 * pp;
            const float* ap = Ab + ((size_t)(b * S + s)) * 64 + o0;  // uniform -> s_load
            const float* dp = Df + ((size_t)(b * S + s)) * 64 + o0;
            float t0 = 0.f;
            #pragma unroll
            for (int j = 0; j < 32; ++j)
                t0 += ap[j] * u[j] + dp[j] * wc[j];
            acc[pp] += t0;
        }
    }

    #pragma unroll
    for (int pp = 0; pp < 2; ++pp) {
        const int b = q * 8 + w + 4 * pp;
        out[((size_t)(b * S + s)) * 64 + lane] = acc[pp];  // coalesced
    }
}

// ---------------------------------------------------------------------------
extern "C" void kernel_launch(void* const* d_in, const int* in_sizes, int n_in,
                              void* d_out, int out_size, void* d_ws, size_t ws_size,
                              hipStream_t stream)
{
    const float* h  = (const float*)d_in[0];
    const float* W0 = (const float*)d_in[1];
    const float* b0 = (const float*)d_in[2];
    const float* Ws = (const float*)d_in[3];
    const float* bs = (const float*)d_in[4];
    const float* W1 = (const float*)d_in[5];
    const float* b1 = (const float*)d_in[6];
    float* out = (float*)d_out;

    float* ws  = (float*)d_ws;
    float* U1T = ws;                       // 4096
    float* Ab  = U1T + 64 * 64;            // 262144
    float* Df  = Ab  + ROWS * 64;          // 262144
    float* C   = Df  + ROWS * 64;          // 262144
    float* P   = C   + ROWS * 64;          // 2048*128 = 262144
    // total: ~4.0 MB of d_ws; every element read is written first each call.

    prep_kernel <<<512, 256, 0, stream>>>(h, W0, b0, Ws, bs, W1, U1T, Ab, Df, C);
    mid_kernel  <<<512, 256, 0, stream>>>(C, W1, P);
    final_kernel<<<512, 256, 0, stream>>>(W1, b1, U1T, Ab, Df, P, out);
}